// Round 6
// baseline (312.424 us; speedup 1.0000x reference)
//
#include <hip/hip_runtime.h>
#include <hip/hip_bf16.h>

#define D 128

typedef __bf16 bf16x8 __attribute__((ext_vector_type(8)));
typedef float f32x16 __attribute__((ext_vector_type(16)));

union U16 { uint4 u; bf16x8 v; };

static __device__ __forceinline__ unsigned short f2bf(float f) {
    unsigned u = __float_as_uint(f);
    unsigned r = (u + 0x7fffu + ((u >> 16) & 1u)) >> 16;   // RNE
    return (unsigned short)r;
}
static __device__ __forceinline__ float bf2f(unsigned short s) {
    return __uint_as_float(((unsigned)s) << 16);
}
static __device__ __forceinline__ float u2f_lo(unsigned x) { return __uint_as_float(x << 16); }
static __device__ __forceinline__ float u2f_hi(unsigned x) { return __uint_as_float(x & 0xffff0000u); }

// ===================== fused weight prep (3 matrices) + cnt zero ================
__global__ __launch_bounds__(256) void k_prep(
        const float* __restrict__ W1, const float* __restrict__ W2, const float* __restrict__ Wf,
        unsigned short* __restrict__ W1h, unsigned short* __restrict__ W1l,
        unsigned short* __restrict__ W2h, unsigned short* __restrict__ W2l,
        unsigned short* __restrict__ Wfh,
        int* __restrict__ cnt, int n) {
    int idx = blockIdx.x * 256 + threadIdx.x;
    if (idx < 3 * 16384) {
        int which = idx >> 14;
        int local = idx & 16383;
        int k = local >> 7, c = local & 127;
        const float* W = (which == 0) ? W1 : (which == 1) ? W2 : Wf;
        float v = W[k * 128 + c];
        unsigned short h = f2bf(v);
        unsigned short l = f2bf(v - bf2f(h));
        if (which == 0) { W1h[c * 128 + k] = h; W1l[c * 128 + k] = l; }
        else if (which == 1) { W2h[c * 128 + k] = h; W2l[c * 128 + k] = l; }
        else { Wfh[c * 128 + k] = h; }
    }
    if (idx < n) cnt[idx] = 0;
}

// ===================== CSR build (counting sort by dst) =====================

__global__ __launch_bounds__(256) void k_hist(const int* __restrict__ dst,
                                              int* __restrict__ cnt, int e) {
    int i = blockIdx.x * 256 + threadIdx.x;
    if (i < e) atomicAdd(&cnt[dst[i]], 1);
}

#define SCAN_CHUNK 1024

__global__ __launch_bounds__(256) void k_scan_local(const int* __restrict__ cnt,
                                                    int* __restrict__ ptr,
                                                    int* __restrict__ sums, int n) {
    __shared__ int tsum[256];
    const int t = threadIdx.x;
    const int base = blockIdx.x * SCAN_CHUNK + t * 4;
    int v[4]; int s = 0;
    #pragma unroll
    for (int i = 0; i < 4; ++i) {
        int idx = base + i;
        v[i] = (idx < n) ? cnt[idx] : 0;
        s += v[i];
    }
    tsum[t] = s;
    __syncthreads();
    for (int off = 1; off < 256; off <<= 1) {
        int x = (t >= off) ? tsum[t - off] : 0;
        __syncthreads();
        tsum[t] += x;
        __syncthreads();
    }
    int run = (t > 0) ? tsum[t - 1] : 0;
    if (t == 255) sums[blockIdx.x] = tsum[255];
    #pragma unroll
    for (int i = 0; i < 4; ++i) {
        int idx = base + i;
        if (idx < n) ptr[idx] = run;
        run += v[i];
    }
}

__global__ __launch_bounds__(256) void k_scan_sums(int* __restrict__ sums, int nChunks) {
    __shared__ int ls[256];
    const int t = threadIdx.x;
    ls[t] = (t < nChunks) ? sums[t] : 0;
    __syncthreads();
    for (int off = 1; off < 256; off <<= 1) {
        int x = (t >= off) ? ls[t - off] : 0;
        __syncthreads();
        ls[t] += x;
        __syncthreads();
    }
    if (t < nChunks) sums[t] = (t > 0) ? ls[t - 1] : 0;
}

__global__ __launch_bounds__(256) void k_scan_add(int* __restrict__ ptr,
                                                  const int* __restrict__ sums,
                                                  int* __restrict__ cnt,
                                                  float* __restrict__ dinv,
                                                  int n, int e) {
    int i = blockIdx.x * 256 + threadIdx.x;
    if (i < n) {
        ptr[i] += sums[i >> 10];
        dinv[i] = rsqrtf((float)(1 + cnt[i]));
        cnt[i] = 0;
    }
    if (i == 0) ptr[n] = e;
}

__global__ __launch_bounds__(256) void k_fill(const int* __restrict__ src,
                                              const int* __restrict__ dst,
                                              const int* __restrict__ ptr,
                                              int* __restrict__ fill,
                                              int* __restrict__ csr_src, int e) {
    int i = blockIdx.x * 256 + threadIdx.x;
    if (i < e) {
        int d = dst[i];
        int slot = ptr[d] + atomicAdd(&fill[d], 1);
        csr_src[slot] = src[i];
    }
}

// ===================== dual-B register-resident MFMA GEMM =======================
// Reads x once: out1 = bf16(x@W1) [hi/lo split, 3 MFMA/ks],
//               out2 = x@Wfc + bias2 [hi only, 2 MFMA/ks].
#define APAD 136   // 272 B row stride, 16B-aligned; 4-way b128 conflict (1.58x, ok)

__global__ __launch_bounds__(256, 2) void k_gemm_dual(
        const float* __restrict__ A,
        const unsigned short* __restrict__ B1h, const unsigned short* __restrict__ B1l,
        const unsigned short* __restrict__ B2h,
        const float* __restrict__ bias2,
        unsigned short* __restrict__ out1,
        float* __restrict__ out2,
        int M, int nTiles) {
    __shared__ __align__(16) unsigned short As[2][32][APAD];

    const int tid = threadIdx.x;
    const int wave = tid >> 6;
    const int lane = tid & 63;
    const int l31 = lane & 31;
    const int quad8 = (lane >> 5) * 8;
    const int col = wave * 32 + l31;

    U16 bh1[8], bl1[8], bh2[8];
    #pragma unroll
    for (int ks = 0; ks < 8; ++ks) {
        const size_t bo = (size_t)col * D + ks * 16 + quad8;
        bh1[ks].u = *(const uint4*)(B1h + bo);
        bl1[ks].u = *(const uint4*)(B1l + bo);
        bh2[ks].u = *(const uint4*)(B2h + bo);
    }
    const float bv = bias2[col];

    for (int t = blockIdx.x; t < nTiles; t += gridDim.x) {
        const int row0 = t * 32;

        #pragma unroll
        for (int i = 0; i < 4; ++i) {
            int f = tid + i * 256;            // float4 index over [32][32]
            int r = f >> 5, c4 = (f & 31) * 4;
            int rg = row0 + r; if (rg >= M) rg = M - 1;
            float4 v = *(const float4*)(A + (size_t)rg * D + c4);
            ushort4 hq, lq;
            hq.x = f2bf(v.x); hq.y = f2bf(v.y); hq.z = f2bf(v.z); hq.w = f2bf(v.w);
            lq.x = f2bf(v.x - bf2f(hq.x)); lq.y = f2bf(v.y - bf2f(hq.y));
            lq.z = f2bf(v.z - bf2f(hq.z)); lq.w = f2bf(v.w - bf2f(hq.w));
            *(ushort4*)&As[0][r][c4] = hq;
            *(ushort4*)&As[1][r][c4] = lq;
        }
        __syncthreads();

        f32x16 acc1, acc2;
        #pragma unroll
        for (int r = 0; r < 16; ++r) { acc1[r] = 0.f; acc2[r] = 0.f; }

        #pragma unroll
        for (int ks = 0; ks < 8; ++ks) {
            U16 ah, al;
            ah.u = *(const uint4*)&As[0][l31][ks * 16 + quad8];
            al.u = *(const uint4*)&As[1][l31][ks * 16 + quad8];
            acc1 = __builtin_amdgcn_mfma_f32_32x32x16_bf16(ah.v, bh1[ks].v, acc1, 0, 0, 0);
            acc1 = __builtin_amdgcn_mfma_f32_32x32x16_bf16(ah.v, bl1[ks].v, acc1, 0, 0, 0);
            acc1 = __builtin_amdgcn_mfma_f32_32x32x16_bf16(al.v, bh1[ks].v, acc1, 0, 0, 0);
            acc2 = __builtin_amdgcn_mfma_f32_32x32x16_bf16(ah.v, bh2[ks].v, acc2, 0, 0, 0);
            acc2 = __builtin_amdgcn_mfma_f32_32x32x16_bf16(al.v, bh2[ks].v, acc2, 0, 0, 0);
        }
        __syncthreads();

        #pragma unroll
        for (int reg = 0; reg < 16; ++reg) {
            const int r = (reg & 3) + 8 * (reg >> 2) + 4 * (lane >> 5);
            const int rg = row0 + r;
            if (rg < M) {
                out1[(size_t)rg * D + col] = f2bf(acc1[reg]);
                out2[(size_t)rg * D + col] = acc2[reg] + bv;
            }
        }
    }
}

// ===================== fused aggregate(layer1) + GEMM(W2) =======================
// Block: gather 32 nodes' relu'd activations into the LDS A-tile (dynamic
// work-stealing over nodes), then MFMA with register-resident W2 hi/lo.
__global__ __launch_bounds__(256, 3) void k_agg_gemm(
        const int* __restrict__ ptr, const int* __restrict__ csr_src,
        const float* __restrict__ dinv,
        const unsigned short* __restrict__ h,     // layer-1 features (bf16)
        const float* __restrict__ bias,
        const unsigned short* __restrict__ Bh, const unsigned short* __restrict__ Bl,
        unsigned short* __restrict__ outh,        // layer-2 features (bf16)
        int N, int nTiles) {
    __shared__ __align__(16) unsigned short As[32][APAD];
    __shared__ int ctr;

    const int tid = threadIdx.x;
    const int wave = tid >> 6;
    const int lane = tid & 63;
    const int l31 = lane & 31;
    const int quad8 = (lane >> 5) * 8;
    const int col = wave * 32 + l31;
    const int glane = tid & 31;

    U16 bh[8], bl[8];
    #pragma unroll
    for (int ks = 0; ks < 8; ++ks) {
        const size_t bo = (size_t)col * D + ks * 16 + quad8;
        bh[ks].u = *(const uint4*)(Bh + bo);
        bl[ks].u = *(const uint4*)(Bl + bo);
    }
    const float4 bvec = *(const float4*)(bias + glane * 4);

    for (int t = blockIdx.x; t < nTiles; t += gridDim.x) {
        const int row0 = t * 32;
        if (tid == 0) ctr = 0;
        __syncthreads();

        // ---- gather phase: 8 groups of 32 lanes steal nodes from the tile ----
        while (true) {
            int q = 0;
            if (glane == 0) q = atomicAdd(&ctr, 1);
            q = __shfl(q, (int)(tid & 32), 64);
            if (q >= 32) break;
            int i = row0 + q; if (i >= N) i = N - 1;

            const int p0 = ptr[i];
            const int p1 = ptr[i + 1];
            const float di = dinv[i];

            float a0 = 0.f, a1 = 0.f, a2 = 0.f, a3 = 0.f;
            int j = p0;
            for (; j + 4 <= p1; j += 4) {
                const int s0 = csr_src[j + 0];
                const int s1 = csr_src[j + 1];
                const int s2 = csr_src[j + 2];
                const int s3 = csr_src[j + 3];
                const float c0 = dinv[s0], c1 = dinv[s1], c2 = dinv[s2], c3 = dinv[s3];
                const uint2 u0 = *(const uint2*)(h + (size_t)s0 * D + glane * 4);
                const uint2 u1 = *(const uint2*)(h + (size_t)s1 * D + glane * 4);
                const uint2 u2 = *(const uint2*)(h + (size_t)s2 * D + glane * 4);
                const uint2 u3 = *(const uint2*)(h + (size_t)s3 * D + glane * 4);
                a0 = fmaf(c0, u2f_lo(u0.x), a0); a1 = fmaf(c0, u2f_hi(u0.x), a1);
                a2 = fmaf(c0, u2f_lo(u0.y), a2); a3 = fmaf(c0, u2f_hi(u0.y), a3);
                a0 = fmaf(c1, u2f_lo(u1.x), a0); a1 = fmaf(c1, u2f_hi(u1.x), a1);
                a2 = fmaf(c1, u2f_lo(u1.y), a2); a3 = fmaf(c1, u2f_hi(u1.y), a3);
                a0 = fmaf(c2, u2f_lo(u2.x), a0); a1 = fmaf(c2, u2f_hi(u2.x), a1);
                a2 = fmaf(c2, u2f_lo(u2.y), a2); a3 = fmaf(c2, u2f_hi(u2.y), a3);
                a0 = fmaf(c3, u2f_lo(u3.x), a0); a1 = fmaf(c3, u2f_hi(u3.x), a1);
                a2 = fmaf(c3, u2f_lo(u3.y), a2); a3 = fmaf(c3, u2f_hi(u3.y), a3);
            }
            for (; j < p1; ++j) {
                const int s = csr_src[j];
                const float c = dinv[s];
                const uint2 u = *(const uint2*)(h + (size_t)s * D + glane * 4);
                a0 = fmaf(c, u2f_lo(u.x), a0);
                a1 = fmaf(c, u2f_hi(u.x), a1);
                a2 = fmaf(c, u2f_lo(u.y), a2);
                a3 = fmaf(c, u2f_hi(u.y), a3);
            }

            const uint2 us = *(const uint2*)(h + (size_t)i * D + glane * 4);
            const float self = di * di;
            float o0 = fmaxf(di * a0 + self * u2f_lo(us.x) + bvec.x, 0.0f);
            float o1 = fmaxf(di * a1 + self * u2f_hi(us.x) + bvec.y, 0.0f);
            float o2 = fmaxf(di * a2 + self * u2f_lo(us.y) + bvec.z, 0.0f);
            float o3 = fmaxf(di * a3 + self * u2f_hi(us.y) + bvec.w, 0.0f);
            ushort4 qv = {f2bf(o0), f2bf(o1), f2bf(o2), f2bf(o3)};
            *(ushort4*)&As[q][glane * 4] = qv;
        }
        __syncthreads();

        // ---- MFMA phase: h2_tile = As @ W2 (hi/lo) ----
        f32x16 acc;
        #pragma unroll
        for (int r = 0; r < 16; ++r) acc[r] = 0.f;

        #pragma unroll
        for (int ks = 0; ks < 8; ++ks) {
            U16 ah;
            ah.u = *(const uint4*)&As[l31][ks * 16 + quad8];
            acc = __builtin_amdgcn_mfma_f32_32x32x16_bf16(ah.v, bh[ks].v, acc, 0, 0, 0);
            acc = __builtin_amdgcn_mfma_f32_32x32x16_bf16(ah.v, bl[ks].v, acc, 0, 0, 0);
        }

        #pragma unroll
        for (int reg = 0; reg < 16; ++reg) {
            const int r = (reg & 3) + 8 * (reg >> 2) + 4 * (lane >> 5);
            const int rg = row0 + r;
            if (rg < N) outh[(size_t)rg * D + col] = f2bf(acc[reg]);
        }
        __syncthreads();   // As reads done before next tile's gather overwrites
    }
}

// ===================== layer-2 gather + bias + relu + residual ==================
__global__ __launch_bounds__(256) void k_gather_bf(const int* __restrict__ ptr,
                                                   const int* __restrict__ csr_src,
                                                   const float* __restrict__ dinv,
                                                   const unsigned short* __restrict__ h,
                                                   const float* __restrict__ bias,
                                                   const float* __restrict__ res,
                                                   float* __restrict__ outf,
                                                   int N) {
    const int g = threadIdx.x >> 5;
    const int lane = threadIdx.x & 31;
    const int i = blockIdx.x * 8 + g;
    if (i >= N) return;

    const int p0 = ptr[i];
    const int p1 = ptr[i + 1];
    const float di = dinv[i];

    float a0 = 0.f, a1 = 0.f, a2 = 0.f, a3 = 0.f;
    int j = p0;
    for (; j + 4 <= p1; j += 4) {
        const int s0 = csr_src[j + 0];
        const int s1 = csr_src[j + 1];
        const int s2 = csr_src[j + 2];
        const int s3 = csr_src[j + 3];
        const float c0 = dinv[s0], c1 = dinv[s1], c2 = dinv[s2], c3 = dinv[s3];
        const uint2 u0 = *(const uint2*)(h + (size_t)s0 * D + lane * 4);
        const uint2 u1 = *(const uint2*)(h + (size_t)s1 * D + lane * 4);
        const uint2 u2 = *(const uint2*)(h + (size_t)s2 * D + lane * 4);
        const uint2 u3 = *(const uint2*)(h + (size_t)s3 * D + lane * 4);
        a0 = fmaf(c0, u2f_lo(u0.x), a0); a1 = fmaf(c0, u2f_hi(u0.x), a1);
        a2 = fmaf(c0, u2f_lo(u0.y), a2); a3 = fmaf(c0, u2f_hi(u0.y), a3);
        a0 = fmaf(c1, u2f_lo(u1.x), a0); a1 = fmaf(c1, u2f_hi(u1.x), a1);
        a2 = fmaf(c1, u2f_lo(u1.y), a2); a3 = fmaf(c1, u2f_hi(u1.y), a3);
        a0 = fmaf(c2, u2f_lo(u2.x), a0); a1 = fmaf(c2, u2f_hi(u2.x), a1);
        a2 = fmaf(c2, u2f_lo(u2.y), a2); a3 = fmaf(c2, u2f_hi(u2.y), a3);
        a0 = fmaf(c3, u2f_lo(u3.x), a0); a1 = fmaf(c3, u2f_hi(u3.x), a1);
        a2 = fmaf(c3, u2f_lo(u3.y), a2); a3 = fmaf(c3, u2f_hi(u3.y), a3);
    }
    for (; j < p1; ++j) {
        const int s = csr_src[j];
        const float c = dinv[s];
        const uint2 u = *(const uint2*)(h + (size_t)s * D + lane * 4);
        a0 = fmaf(c, u2f_lo(u.x), a0);
        a1 = fmaf(c, u2f_hi(u.x), a1);
        a2 = fmaf(c, u2f_lo(u.y), a2);
        a3 = fmaf(c, u2f_hi(u.y), a3);
    }

    const uint2 us = *(const uint2*)(h + (size_t)i * D + lane * 4);
    const float4 bv = *(const float4*)(bias + lane * 4);
    const float self = di * di;
    float o0 = fmaxf(di * a0 + self * u2f_lo(us.x) + bv.x, 0.0f);
    float o1 = fmaxf(di * a1 + self * u2f_hi(us.x) + bv.y, 0.0f);
    float o2 = fmaxf(di * a2 + self * u2f_lo(us.y) + bv.z, 0.0f);
    float o3 = fmaxf(di * a3 + self * u2f_hi(us.y) + bv.w, 0.0f);
    const float4 rv = *(const float4*)(res + (size_t)i * D + lane * 4);
    float4 o = {o0 + rv.x, o1 + rv.y, o2 + rv.z, o3 + rv.w};
    *(float4*)(outf + (size_t)i * D + lane * 4) = o;
}

// ===================== launch =====================

extern "C" void kernel_launch(void* const* d_in, const int* in_sizes, int n_in,
                              void* d_out, int out_size, void* d_ws, size_t ws_size,
                              hipStream_t stream) {
    const int N = in_sizes[0] / D;     // 100000
    const int E = in_sizes[1] / 2;     // 600000

    const float* x   = (const float*)d_in[0];
    const int*   ei  = (const int*)d_in[1];
    const int*   src = ei;
    const int*   dst = ei + E;
    const float* W1  = (const float*)d_in[2];
    const float* b1  = (const float*)d_in[3];
    const float* W2  = (const float*)d_in[4];
    const float* b2  = (const float*)d_in[5];
    const float* Wfc = (const float*)d_in[6];
    const float* bfc = (const float*)d_in[7];
    float* out = (float*)d_out;

    // ---- workspace layout ----
    char* ws = (char*)d_ws;
    size_t off = 0;
    auto alloc = [&](size_t bytes) { char* p = ws + off; off += (bytes + 255) & ~(size_t)255; return p; };
    float* dinv    = (float*)alloc((size_t)N * 4);
    int*   cnt     = (int*)  alloc((size_t)N * 4);
    int*   ptr     = (int*)  alloc((size_t)(N + 1) * 4);
    int*   sums    = (int*)  alloc(256 * 4);
    int*   csr_src = (int*)  alloc((size_t)E * 4);
    unsigned short* W1h = (unsigned short*)alloc(128 * 128 * 2);
    unsigned short* W1l = (unsigned short*)alloc(128 * 128 * 2);
    unsigned short* W2h = (unsigned short*)alloc(128 * 128 * 2);
    unsigned short* W2l = (unsigned short*)alloc(128 * 128 * 2);
    unsigned short* Wfh = (unsigned short*)alloc(128 * 128 * 2);
    unsigned short* h1  = (unsigned short*)alloc((size_t)N * D * 2);  // layer-1 features
    unsigned short* h2  = (unsigned short*)alloc((size_t)N * D * 2);  // layer-2 features

    const int nBlk    = (N + 255) / 256;
    const int eBlk    = (E + 255) / 256;
    const int aBlk    = (N + 7) / 8;
    const int nChunks = (N + SCAN_CHUNK - 1) / SCAN_CHUNK;
    const int nTiles  = (N + 31) / 32;
    const int gDual   = nTiles < 512 ? nTiles : 512;    // 2 blocks/CU
    const int gAgg    = nTiles < 768 ? nTiles : 768;    // 3 blocks/CU
    const int pBlk    = (nBlk > 192) ? nBlk : 192;

    // ---- weight prep + cnt zero ----
    k_prep<<<pBlk, 256, 0, stream>>>(W1, W2, Wfc, W1h, W1l, W2h, W2l, Wfh, cnt, N);

    // ---- CSR build + dinv ----
    k_hist<<<eBlk, 256, 0, stream>>>(dst, cnt, E);
    k_scan_local<<<nChunks, 256, 0, stream>>>(cnt, ptr, sums, N);
    k_scan_sums<<<1, 256, 0, stream>>>(sums, nChunks);
    k_scan_add<<<nBlk, 256, 0, stream>>>(ptr, sums, cnt, dinv, N, E);
    k_fill<<<eBlk, 256, 0, stream>>>(src, dst, ptr, cnt, csr_src, E);

    // ---- h1 = bf16(x@W1) ; out = x@Wfc + bfc (x read once) ----
    k_gemm_dual<<<gDual, 256, 0, stream>>>(x, W1h, W1l, Wfh, bfc, h1, out, N, nTiles);

    // ---- layer-1 aggregate fused with W2 GEMM: h2 = bf16(relu(agg(h1)+b1) @ W2) ----
    k_agg_gemm<<<gAgg, 256, 0, stream>>>(ptr, csr_src, dinv, h1, b1, W2h, W2l, h2, N, nTiles);

    // ---- layer-2 aggregate + bias + relu + residual ----
    k_gather_bf<<<aBlk, 256, 0, stream>>>(ptr, csr_src, dinv, h2, b2, out, out, N);
}